// Round 6
// baseline (337.403 us; speedup 1.0000x reference)
//
#include <hip/hip_runtime.h>
#include <hip/hip_bf16.h>

// ---- constants for this problem ----
// B=8, T=1024, C=1024, H=16, Dh=64 ; M = B*T = 8192, K = C = 1024
#define KDIM 1024

typedef __bf16  bf16x8  __attribute__((ext_vector_type(8)));
typedef float   floatx4 __attribute__((ext_vector_type(4)));

__device__ inline short f2bf(float f) {
    unsigned u = __float_as_uint(f);
    u += 0x7fffu + ((u >> 16) & 1u);     // round-to-nearest-even
    return (short)(u >> 16);
}
__device__ inline float bf2f(short s) {
    return __uint_as_float(((unsigned)(unsigned short)s) << 16);
}

__device__ inline floatx4 mfma16(bf16x8 a, bf16x8 b, floatx4 c) {
    return __builtin_amdgcn_mfma_f32_16x16x32_bf16(a, b, c, 0, 0, 0);
}

// async global->LDS, 16B per lane.  lds pointer must be wave-uniform base;
// HW adds lane*16.
__device__ inline void load_lds16(const void* g, void* l) {
    __builtin_amdgcn_global_load_lds(
        (__attribute__((address_space(1))) void*)(unsigned long long)g,
        (__attribute__((address_space(3))) void*)(unsigned)(unsigned long long)l,
        16, 0, 0);
}

// ---------------- LayerNorm: one block per row (C=1024) ----------------
template <bool BF16IN>
__global__ __launch_bounds__(256) void ln_kernel(
    const void* __restrict__ xv, const float* __restrict__ g,
    const float* __restrict__ be, short* __restrict__ out)
{
    const int row = blockIdx.x, tid = threadIdx.x;
    float4 v;
    if constexpr (BF16IN) {
        const short4 s4 = ((const short4*)xv)[(size_t)row * 256 + tid];
        v.x = bf2f(s4.x); v.y = bf2f(s4.y); v.z = bf2f(s4.z); v.w = bf2f(s4.w);
    } else {
        v = ((const float4*)xv)[(size_t)row * 256 + tid];
    }
    float s  = v.x + v.y + v.z + v.w;
    float s2 = v.x * v.x + v.y * v.y + v.z * v.z + v.w * v.w;
    #pragma unroll
    for (int off = 32; off; off >>= 1) {
        s  += __shfl_down(s, off);
        s2 += __shfl_down(s2, off);
    }
    __shared__ float red1[4], red2[4];
    const int w = tid >> 6, lane = tid & 63;
    if (lane == 0) { red1[w] = s; red2[w] = s2; }
    __syncthreads();
    s  = red1[0] + red1[1] + red1[2] + red1[3];
    s2 = red2[0] + red2[1] + red2[2] + red2[3];
    const float mean = s * (1.0f / 1024.0f);
    const float var  = s2 * (1.0f / 1024.0f) - mean * mean;
    const float rstd = rsqrtf(var + 1e-5f);
    const float4 gg = ((const float4*)g)[tid];
    const float4 bb = ((const float4*)be)[tid];
    short4 o;
    o.x = f2bf((v.x - mean) * rstd * gg.x + bb.x);
    o.y = f2bf((v.y - mean) * rstd * gg.y + bb.y);
    o.z = f2bf((v.z - mean) * rstd * gg.z + bb.z);
    o.w = f2bf((v.w - mean) * rstd * gg.w + bb.w);
    *(short4*)(out + (size_t)row * 1024 + tid * 4) = o;
}

// -------- all weight packs in one dispatch --------
// bx <  96 : Wq/Wk/Wv [H,C,Dh] -> qkvT [3072][1024]
// bx in [96,128): WprojT ; [128,160): W1T ; [160,192): W2T  (transpose-pack)
__global__ void pack_all(const float* __restrict__ Wq, const float* __restrict__ Wk,
                         const float* __restrict__ Wv, const float* __restrict__ Wproj,
                         const float* __restrict__ W1, const float* __restrict__ W2,
                         short* __restrict__ qkvT, short* __restrict__ projT,
                         short* __restrict__ w1T, short* __restrict__ w2T)
{
    __shared__ float tile[32][33];
    const int bx = blockIdx.x, c0 = blockIdx.y * 32;
    const int tx = threadIdx.x, ty = threadIdx.y;   // 32 x 8
    if (bx < 96) {
        const int n0 = bx * 32;
        const int grp = n0 >> 10;
        const float* W = (grp == 0) ? Wq : (grp == 1 ? Wk : Wv);
        const int nb = n0 & 1023, hh = nb >> 6, d0 = nb & 63;
        #pragma unroll
        for (int j = 0; j < 32; j += 8)
            tile[ty + j][tx] = W[hh * 65536 + (c0 + ty + j) * 64 + d0 + tx];
        __syncthreads();
        #pragma unroll
        for (int j = 0; j < 32; j += 8)
            qkvT[(size_t)(n0 + ty + j) * 1024 + c0 + tx] = f2bf(tile[tx][ty + j]);
    } else {
        const int which = (bx - 96) >> 5;
        const int n0 = ((bx - 96) & 31) * 32;
        const float* src = (which == 0) ? Wproj : (which == 1 ? W1 : W2);
        short* dst = (which == 0) ? projT : (which == 1 ? w1T : w2T);
        #pragma unroll
        for (int j = 0; j < 32; j += 8)
            tile[ty + j][tx] = src[(size_t)(c0 + ty + j) * 1024 + n0 + tx];
        __syncthreads();
        #pragma unroll
        for (int j = 0; j < 32; j += 8)
            dst[(size_t)(n0 + ty + j) * 1024 + c0 + tx] = f2bf(tile[tx][ty + j]);
    }
}

// ---------------- GEMM: C[M,N] = A[M,K] * BT[N,K]^T, bf16 MFMA ----------------
// TM x 128 tile (TM=128 or 64), 4 waves, BK=32, single-barrier double-buffered
// K-loop: barrier -> issue async stage of chunk c+1 -> compute chunk c, so the
// staging has the whole compute phase in flight before the next barrier drain.
// XOR-swizzled LDS (conflict-free ds_read_b128).  XCD remap: each XCD owns
// (M/TM)/8 consecutive row-panels x all col-panels (A+B working set < 4MB L2).
// SWAP=true: mfma(B,A) -> C/D register axis = output COLUMN (vector epilogues).
// EPI 0 (SWAP): QK scatter (Q scaled 0.125)   EPI 2 (SWAP): relu bf16 + bias
// EPI 3 (!SWAP): V transposed scatter
// EPI 4 (SWAP): bf16 out = acc + bias + residF32
// EPI 5 (SWAP): f32 out = acc + bias + residBf16
template <int EPI, bool SWAP, int TM>
__global__ __launch_bounds__(256, 4) void gemm_bt(
    const short* __restrict__ A, const short* __restrict__ BT, int N,
    const float* __restrict__ bias, const float* __restrict__ residF,
    const short* __restrict__ residH,
    float* __restrict__ outF, short* __restrict__ outH,
    short* __restrict__ qO, short* __restrict__ kO, short* __restrict__ vtO)
{
    constexpr int IT = TM / 32;              // row-tiles per wave
    constexpr int PP = (8192 / TM) / 8;      // row panels per XCD
    const int tid = threadIdx.x, lane = tid & 63, w = tid >> 6;
    const int wm = w >> 1, wn = w & 1;
    const int mi = lane & 15, quad = lane >> 4;
    const int lid = blockIdx.x + gridDim.x * blockIdx.y;
    const int xcd = lid & 7, i8 = lid >> 3;
    const int rowBase = (xcd * PP + (i8 % PP)) * TM;
    const int colBase = (i8 / PP) * 128;

    __shared__ alignas(16) short As[2][TM * 32];
    __shared__ alignas(16) short Bs[2][128 * 32];

    const floatx4 z4 = {0.f, 0.f, 0.f, 0.f};
    floatx4 acc[IT][4];
    #pragma unroll
    for (int i = 0; i < IT; ++i)
        #pragma unroll
        for (int j = 0; j < 4; ++j) acc[i][j] = z4;

    auto stage = [&](int k0, int buf) {
        #pragma unroll
        for (int i = 0; i < TM / 64; ++i) {       // A: TM*4 chunks
            const int cb = i * 256 + w * 64;      // wave-uniform chunk base
            const int chunk = cb + lane;
            const int r = chunk >> 2, cc = chunk & 3;
            const int csw = cc ^ ((r >> 1) & 3);  // source-chunk swizzle
            load_lds16(A + (size_t)(rowBase + r) * KDIM + k0 + csw * 8,
                       (char*)As[buf] + cb * 16);
        }
        #pragma unroll
        for (int i = 0; i < 2; ++i) {             // B: 512 chunks
            const int cb = i * 256 + w * 64;
            const int chunk = cb + lane;
            const int r = chunk >> 2, cc = chunk & 3;
            const int csw = cc ^ ((r >> 1) & 3);
            load_lds16(BT + (size_t)(colBase + r) * KDIM + k0 + csw * 8,
                       (char*)Bs[buf] + cb * 16);
        }
    };

    auto compute = [&](const short* Ac, const short* Bc) {
        bf16x8 af[IT], bfv[4];
        #pragma unroll
        for (int it = 0; it < IT; ++it) {
            const int ra = wm * (TM / 2) + it * 16 + mi;
            af[it] = *(const bf16x8*)(Ac + ra * 32 + ((quad ^ ((ra >> 1) & 3)) << 3));
        }
        #pragma unroll
        for (int jt = 0; jt < 4; ++jt) {
            const int rb = wn * 64 + jt * 16 + mi;
            bfv[jt] = *(const bf16x8*)(Bc + rb * 32 + ((quad ^ ((rb >> 1) & 3)) << 3));
        }
        #pragma unroll
        for (int it = 0; it < IT; ++it)
            #pragma unroll
            for (int jt = 0; jt < 4; ++jt) {
                if constexpr (SWAP)
                    acc[it][jt] = mfma16(bfv[jt], af[it], acc[it][jt]);
                else
                    acc[it][jt] = mfma16(af[it], bfv[jt], acc[it][jt]);
            }
    };

    stage(0, 0);
    #pragma unroll 1
    for (int c = 0; c < KDIM / 32; c += 2) {
        __syncthreads();                          // drains stage(c) into buf0
        if (c + 1 < KDIM / 32) stage((c + 1) * 32, 1);
        compute(As[0], Bs[0]);
        __syncthreads();                          // drains stage(c+1) into buf1
        if (c + 2 < KDIM / 32) stage((c + 2) * 32, 0);
        compute(As[1], Bs[1]);
    }

    if constexpr (SWAP) {
        // lane -> row = ...+mi ; registers -> 4 consecutive cols (quad*4+r)
        #pragma unroll
        for (int it = 0; it < IT; ++it) {
            const int row = rowBase + wm * (TM / 2) + it * 16 + mi;
            #pragma unroll
            for (int jt = 0; jt < 4; ++jt) {
                const int col0 = colBase + wn * 64 + jt * 16 + quad * 4;
                const floatx4 a4 = acc[it][jt];
                if constexpr (EPI == 0) {
                    if (colBase < 1024) {
                        short4 o;
                        o.x = f2bf(a4[0] * 0.125f); o.y = f2bf(a4[1] * 0.125f);
                        o.z = f2bf(a4[2] * 0.125f); o.w = f2bf(a4[3] * 0.125f);
                        *(short4*)(qO + (size_t)row * 1024 + col0) = o;
                    } else {
                        short4 o;
                        o.x = f2bf(a4[0]); o.y = f2bf(a4[1]);
                        o.z = f2bf(a4[2]); o.w = f2bf(a4[3]);
                        *(short4*)(kO + (size_t)row * 1024 + (col0 - 1024)) = o;
                    }
                } else if constexpr (EPI == 2) {
                    const float4 b4 = *(const float4*)(bias + col0);
                    short4 o;
                    o.x = f2bf(fmaxf(a4[0] + b4.x, 0.f));
                    o.y = f2bf(fmaxf(a4[1] + b4.y, 0.f));
                    o.z = f2bf(fmaxf(a4[2] + b4.z, 0.f));
                    o.w = f2bf(fmaxf(a4[3] + b4.w, 0.f));
                    *(short4*)(outH + (size_t)row * N + col0) = o;
                } else if constexpr (EPI == 4) {
                    const float4 b4 = *(const float4*)(bias + col0);
                    const float4 r4 = *(const float4*)(residF + (size_t)row * N + col0);
                    short4 o;
                    o.x = f2bf(a4[0] + b4.x + r4.x);
                    o.y = f2bf(a4[1] + b4.y + r4.y);
                    o.z = f2bf(a4[2] + b4.z + r4.z);
                    o.w = f2bf(a4[3] + b4.w + r4.w);
                    *(short4*)(outH + (size_t)row * N + col0) = o;
                } else {  // EPI == 5
                    const float4 b4 = *(const float4*)(bias + col0);
                    const short4 r4 = *(const short4*)(residH + (size_t)row * N + col0);
                    float4 o;
                    o.x = a4[0] + b4.x + bf2f(r4.x);
                    o.y = a4[1] + b4.y + bf2f(r4.y);
                    o.z = a4[2] + b4.z + bf2f(r4.z);
                    o.w = a4[3] + b4.w + bf2f(r4.w);
                    *(float4*)(outF + (size_t)row * N + col0) = o;
                }
            }
        }
    } else {
        // EPI 3: V transposed. lane -> weight col c ; registers -> 4 consecutive t
        #pragma unroll
        for (int it = 0; it < IT; ++it) {
            const int row0 = rowBase + wm * (TM / 2) + it * 16 + quad * 4;
            const int bb = row0 >> 10, t0 = row0 & 1023;
            #pragma unroll
            for (int jt = 0; jt < 4; ++jt) {
                const int c = colBase + wn * 64 + jt * 16 + mi;
                const floatx4 a4 = acc[it][jt];
                short4 o;
                o.x = f2bf(a4[0]); o.y = f2bf(a4[1]);
                o.z = f2bf(a4[2]); o.w = f2bf(a4[3]);
                *(short4*)(vtO + ((size_t)bb << 20) + ((size_t)c << 10) + t0) = o;
            }
        }
    }
}

// ---------------- Flash attention (causal), bf16 MFMA ----------------
// Triangle-balanced: block owns q-tiles pi and 15-pi; K/V staged once per
// s-tile, applied to both q-tiles.  XCD-remapped 1D grid (1024 blocks).
#define PSTR 88   // P row stride in shorts (176 B: 16B-aligned)
__device__ __forceinline__ void attn_qk_pv(
    const bf16x8 qf0, const bf16x8 qf1,
    floatx4 (&o)[4], float (&lsum)[4],
    const short* Ks, const short* Vs, short* myP,
    const int mi, const int quad, const int kq, const int diagRowOff)
{
    const floatx4 z4 = {0.f, 0.f, 0.f, 0.f};
    const bool diag = diagRowOff >= 0;
    floatx4 sa[4];
    #pragma unroll
    for (int j = 0; j < 4; ++j) {
        const int row = j * 16 + mi;
        const int sw = row & 7;
        floatx4 s4 = z4;
        s4 = mfma16(qf0, *(const bf16x8*)(Ks + row * 64 + ((quad ^ sw) << 3)), s4);
        s4 = mfma16(qf1, *(const bf16x8*)(Ks + row * 64 + (((quad + 4) ^ sw) << 3)), s4);
        sa[j] = s4;
    }
    #pragma unroll
    for (int j = 0; j < 4; ++j)
        #pragma unroll
        for (int r = 0; r < 4; ++r) {
            float p = __expf(sa[j][r]);
            if (diag && (j * 16 + mi > diagRowOff + quad * 4 + r)) p = 0.f;
            lsum[r] += p;
            myP[(quad * 4 + r) * PSTR + j * 16 + mi] = f2bf(p);
        }
    __asm__ volatile("s_waitcnt lgkmcnt(0)" ::: "memory");
    const bf16x8 pf0 = *(const bf16x8*)(myP + mi * PSTR + kq);
    const bf16x8 pf1 = *(const bf16x8*)(myP + mi * PSTR + 32 + kq);
    #pragma unroll
    for (int d = 0; d < 4; ++d) {
        const int row = d * 16 + mi;
        const int sw = row & 7;
        o[d] = mfma16(pf0, *(const bf16x8*)(Vs + row * 64 + ((quad ^ sw) << 3)), o[d]);
        o[d] = mfma16(pf1, *(const bf16x8*)(Vs + row * 64 + (((quad + 4) ^ sw) << 3)), o[d]);
    }
}

__global__ __launch_bounds__(256, 4) void flash_attn(
    const short* __restrict__ Q, const short* __restrict__ K,
    const short* __restrict__ Vt, short* __restrict__ O)
{
    const int tid = threadIdx.x, lane = tid & 63, w = tid >> 6;
    const int mi = lane & 15, quad = lane >> 4, kq = quad * 8;
    const int lid = blockIdx.x;
    const int xcd = lid & 7, i8 = lid >> 3;
    const int bh = xcd * 16 + (i8 & 15);
    const int pi = i8 >> 4;
    const int h = bh & 15, b = bh >> 4;
    const int tA = pi, tB = 15 - pi;
    const int qbA = tA * 64, qbB = tB * 64;

    __shared__ alignas(16) short Ks[64 * 64];       // [s][d] swizzled, 8 KB
    __shared__ alignas(16) short Vs[64 * 64];       // [d][s] swizzled, 8 KB
    __shared__ alignas(16) short Ps[4][16 * PSTR];  // per-wave P

    const size_t qoffA = ((size_t)(b * 1024 + qbA + w * 16 + mi)) * 1024 + h * 64;
    const size_t qoffB = ((size_t)(b * 1024 + qbB + w * 16 + mi)) * 1024 + h * 64;
    const bf16x8 qA0 = *(const bf16x8*)(Q + qoffA + kq);
    const bf16x8 qA1 = *(const bf16x8*)(Q + qoffA + 32 + kq);
    const bf16x8 qB0 = *(const bf16x8*)(Q + qoffB + kq);
    const bf16x8 qB1 = *(const bf16x8*)(Q + qoffB + 32 + kq);

    const floatx4 z4 = {0.f, 0.f, 0.f, 0.f};
    floatx4 oA[4], oB[4];
    float lA[4], lB[4];
    #pragma unroll
    for (int i = 0; i < 4; ++i) { oA[i] = z4; oB[i] = z4; lA[i] = 0.f; lB[i] = 0.f; }

    short* myP = &Ps[w][0];
    for (int t = 0; t <= tB; ++t) {
        const int s0 = t * 64;
        __syncthreads();
        #pragma unroll
        for (int i = 0; i < 2; ++i) {
            const int cb = i * 256 + w * 64;       // wave-uniform chunk base
            const int chunk = cb + lane;
            const int r = chunk >> 3, c = chunk & 7;
            const int csw = c ^ (r & 7);           // swizzle: slot(r,c) <- chunk c^(r&7)
            load_lds16(K + ((size_t)(b * 1024 + s0 + r)) * 1024 + h * 64 + csw * 8,
                       (char*)Ks + cb * 16);
            load_lds16(Vt + ((size_t)b << 20) + ((size_t)(h * 64 + r) << 10) + s0 + csw * 8,
                       (char*)Vs + cb * 16);
        }
        __syncthreads();

        if (t <= tA)
            attn_qk_pv(qA0, qA1, oA, lA, Ks, Vs, myP, mi, quad, kq,
                       (t == tA) ? (w * 16) : -1);
        attn_qk_pv(qB0, qB1, oB, lB, Ks, Vs, myP, mi, quad, kq,
                   (t == tB) ? (w * 16) : -1);
    }

    #pragma unroll
    for (int r = 0; r < 4; ++r) {
        float sA = lA[r], sB = lB[r];
        #pragma unroll
        for (int off = 1; off < 16; off <<= 1) {
            sA += __shfl_xor(sA, off);
            sB += __shfl_xor(sB, off);
        }
        lA[r] = 1.0f / sA;
        lB[r] = 1.0f / sB;
    }
    #pragma unroll
    for (int d = 0; d < 4; ++d)
        #pragma unroll
        for (int r = 0; r < 4; ++r) {
            const int col = h * 64 + d * 16 + mi;
            const int rowA = b * 1024 + qbA + w * 16 + quad * 4 + r;
            const int rowB = b * 1024 + qbB + w * 16 + quad * 4 + r;
            O[(size_t)rowA * 1024 + col] = f2bf(oA[d][r] * lA[r]);
            O[(size_t)rowB * 1024 + col] = f2bf(oB[d][r] * lB[r]);
        }
}

// ---------------- host launcher ----------------
extern "C" void kernel_launch(void* const* d_in, const int* in_sizes, int n_in,
                              void* d_out, int out_size, void* d_ws, size_t ws_size,
                              hipStream_t stream)
{
    (void)in_sizes; (void)n_in; (void)out_size; (void)ws_size;
    const float* x     = (const float*)d_in[0];
    const float* Wq    = (const float*)d_in[1];
    const float* Wk    = (const float*)d_in[2];
    const float* Wv    = (const float*)d_in[3];
    const float* Wproj = (const float*)d_in[4];
    const float* bproj = (const float*)d_in[5];
    const float* W1    = (const float*)d_in[6];
    const float* b1    = (const float*)d_in[7];
    const float* W2    = (const float*)d_in[8];
    const float* b2    = (const float*)d_in[9];
    const float* g1    = (const float*)d_in[10];
    const float* be1   = (const float*)d_in[11];
    const float* g2    = (const float*)d_in[12];
    const float* be2   = (const float*)d_in[13];
    float* out = (float*)d_out;

    char* ws = (char*)d_ws;
    const size_t MB = 1u << 20;
    short* Qb     = (short*)(ws + 0 * MB);    // 16 MB  [8192][1024] bf16
    short* Kb     = (short*)(ws + 16 * MB);   // 16 MB  [8192][1024] bf16
    short* Vtb    = (short*)(ws + 32 * MB);   // 16 MB  [B][C][T] bf16
    short* XN     = (short*)(ws + 48 * MB);   // 16 MB  xn then xn2
    short* AT     = (short*)(ws + 64 * MB);   // 16 MB  attn then h
    short* R2b    = (short*)(ws + 80 * MB);   // 16 MB  resid2 bf16
    short* WqkvT  = (short*)(ws + 112 * MB);  // 6 MB
    short* WprojT = (short*)(ws + 118 * MB);  // 2 MB
    short* W1T    = (short*)(ws + 120 * MB);  // 2 MB
    short* W2T    = (short*)(ws + 122 * MB);  // 2 MB

    pack_all<<<dim3(192, 32), dim3(32, 8), 0, stream>>>(
        Wq, Wk, Wv, Wproj, W1, W2, WqkvT, WprojT, W1T, W2T);

    ln_kernel<false><<<8192, 256, 0, stream>>>(x, g1, be1, XN);

    // QK part (cols 0..2047 of WqkvT), swapped-operand epilogue
    gemm_bt<0, true, 128><<<dim3(16, 64), 256, 0, stream>>>(XN, WqkvT, 1024,
        nullptr, nullptr, nullptr, nullptr, nullptr, Qb, Kb, nullptr);
    // V part (cols 2048..3071), normal order -> transposed store, TM=64
    gemm_bt<3, false, 64><<<dim3(8, 128), 256, 0, stream>>>(XN, WqkvT + 2048 * KDIM, 1024,
        nullptr, nullptr, nullptr, nullptr, nullptr, nullptr, nullptr, Vtb);

    flash_attn<<<1024, 256, 0, stream>>>(Qb, Kb, Vtb, AT);

    // proj: R2b (bf16) = attn @ Wproj + bproj + x
    gemm_bt<4, true, 64><<<dim3(8, 128), 256, 0, stream>>>(AT, WprojT, 1024,
        bproj, x, nullptr, nullptr, R2b, nullptr, nullptr, nullptr);

    ln_kernel<true><<<8192, 256, 0, stream>>>(R2b, g2, be2, XN);

    gemm_bt<2, true, 64><<<dim3(8, 128), 256, 0, stream>>>(XN, W1T, 1024,
        b1, nullptr, nullptr, nullptr, AT, nullptr, nullptr, nullptr);

    // out (fp32) = h @ W2 + b2 + R2b
    gemm_bt<5, true, 64><<<dim3(8, 128), 256, 0, stream>>>(AT, W2T, 1024,
        b2, nullptr, R2b, out, nullptr, nullptr, nullptr, nullptr);
}

// Round 7
// 314.771 us; speedup vs baseline: 1.0719x; 1.0719x over previous
//
#include <hip/hip_runtime.h>
#include <hip/hip_bf16.h>

// ---- constants for this problem ----
// B=8, T=1024, C=1024, H=16, Dh=64 ; M = B*T = 8192, K = C = 1024
#define KDIM 1024

typedef __bf16  bf16x8  __attribute__((ext_vector_type(8)));
typedef float   floatx4 __attribute__((ext_vector_type(4)));

__device__ inline short f2bf(float f) {
    unsigned u = __float_as_uint(f);
    u += 0x7fffu + ((u >> 16) & 1u);     // round-to-nearest-even
    return (short)(u >> 16);
}
__device__ inline float bf2f(short s) {
    return __uint_as_float(((unsigned)(unsigned short)s) << 16);
}
// packed f32x2 -> bf16x2 (v_cvt_pk_bf16_f32)
__device__ inline unsigned pk2bf(float x, float y) {
    __hip_bfloat162 h = __float22bfloat162_rn(make_float2(x, y));
    return *reinterpret_cast<unsigned*>(&h);
}
// raw v_exp_f32: computes 2^x in one VALU op
__device__ inline float exp2_hw(float x) {
    float r;
    __asm__("v_exp_f32 %0, %1" : "=v"(r) : "v"(x));
    return r;
}

__device__ inline floatx4 mfma16(bf16x8 a, bf16x8 b, floatx4 c) {
    return __builtin_amdgcn_mfma_f32_16x16x32_bf16(a, b, c, 0, 0, 0);
}

// async global->LDS, 16B per lane.  lds pointer must be wave-uniform base;
// HW adds lane*16.
__device__ inline void load_lds16(const void* g, void* l) {
    __builtin_amdgcn_global_load_lds(
        (__attribute__((address_space(1))) void*)(unsigned long long)g,
        (__attribute__((address_space(3))) void*)(unsigned)(unsigned long long)l,
        16, 0, 0);
}

// ---------------- LayerNorm: one block per row (C=1024) ----------------
template <bool BF16IN>
__global__ __launch_bounds__(256) void ln_kernel(
    const void* __restrict__ xv, const float* __restrict__ g,
    const float* __restrict__ be, short* __restrict__ out)
{
    const int row = blockIdx.x, tid = threadIdx.x;
    float4 v;
    if constexpr (BF16IN) {
        const short4 s4 = ((const short4*)xv)[(size_t)row * 256 + tid];
        v.x = bf2f(s4.x); v.y = bf2f(s4.y); v.z = bf2f(s4.z); v.w = bf2f(s4.w);
    } else {
        v = ((const float4*)xv)[(size_t)row * 256 + tid];
    }
    float s  = v.x + v.y + v.z + v.w;
    float s2 = v.x * v.x + v.y * v.y + v.z * v.z + v.w * v.w;
    #pragma unroll
    for (int off = 32; off; off >>= 1) {
        s  += __shfl_down(s, off);
        s2 += __shfl_down(s2, off);
    }
    __shared__ float red1[4], red2[4];
    const int w = tid >> 6, lane = tid & 63;
    if (lane == 0) { red1[w] = s; red2[w] = s2; }
    __syncthreads();
    s  = red1[0] + red1[1] + red1[2] + red1[3];
    s2 = red2[0] + red2[1] + red2[2] + red2[3];
    const float mean = s * (1.0f / 1024.0f);
    const float var  = s2 * (1.0f / 1024.0f) - mean * mean;
    const float rstd = rsqrtf(var + 1e-5f);
    const float4 gg = ((const float4*)g)[tid];
    const float4 bb = ((const float4*)be)[tid];
    const unsigned o01 = pk2bf((v.x - mean) * rstd * gg.x + bb.x,
                               (v.y - mean) * rstd * gg.y + bb.y);
    const unsigned o23 = pk2bf((v.z - mean) * rstd * gg.z + bb.z,
                               (v.w - mean) * rstd * gg.w + bb.w);
    *(uint2*)(out + (size_t)row * 1024 + tid * 4) = make_uint2(o01, o23);
}

// -------- all weight packs in one dispatch --------
__global__ void pack_all(const float* __restrict__ Wq, const float* __restrict__ Wk,
                         const float* __restrict__ Wv, const float* __restrict__ Wproj,
                         const float* __restrict__ W1, const float* __restrict__ W2,
                         short* __restrict__ qkvT, short* __restrict__ projT,
                         short* __restrict__ w1T, short* __restrict__ w2T)
{
    __shared__ float tile[32][33];
    const int bx = blockIdx.x, c0 = blockIdx.y * 32;
    const int tx = threadIdx.x, ty = threadIdx.y;   // 32 x 8
    if (bx < 96) {
        const int n0 = bx * 32;
        const int grp = n0 >> 10;
        const float* W = (grp == 0) ? Wq : (grp == 1 ? Wk : Wv);
        const int nb = n0 & 1023, hh = nb >> 6, d0 = nb & 63;
        #pragma unroll
        for (int j = 0; j < 32; j += 8)
            tile[ty + j][tx] = W[hh * 65536 + (c0 + ty + j) * 64 + d0 + tx];
        __syncthreads();
        #pragma unroll
        for (int j = 0; j < 32; j += 8)
            qkvT[(size_t)(n0 + ty + j) * 1024 + c0 + tx] = f2bf(tile[tx][ty + j]);
    } else {
        const int which = (bx - 96) >> 5;
        const int n0 = ((bx - 96) & 31) * 32;
        const float* src = (which == 0) ? Wproj : (which == 1 ? W1 : W2);
        short* dst = (which == 0) ? projT : (which == 1 ? w1T : w2T);
        #pragma unroll
        for (int j = 0; j < 32; j += 8)
            tile[ty + j][tx] = src[(size_t)(c0 + ty + j) * 1024 + n0 + tx];
        __syncthreads();
        #pragma unroll
        for (int j = 0; j < 32; j += 8)
            dst[(size_t)(n0 + ty + j) * 1024 + c0 + tx] = f2bf(tile[tx][ty + j]);
    }
}

// ---------------- GEMM: C[M,N] = A[M,K] * BT[N,K]^T, bf16 MFMA ----------------
// 128x128 tile, 4 waves, BK=32, single-barrier double-buffered K-loop:
// barrier -> issue async stage of chunk c+1 -> compute chunk c.
// XOR-swizzled LDS (conflict-free ds_read_b128).  XCD remap: each XCD owns
// 8 consecutive row-panels x all col-panels.
// SWAP=true: mfma(B,A) -> C/D register axis = output COLUMN (vector epilogues).
// EPI 0 (SWAP): QK scatter (Q scaled 0.125*log2e)  EPI 2 (SWAP): relu bf16 + bias
// EPI 3 (!SWAP): V transposed scatter
// EPI 4 (SWAP): bf16 out = acc + bias + residF32
// EPI 5 (SWAP): f32 out = acc + bias + residBf16
template <int EPI, bool SWAP>
__global__ __launch_bounds__(256, 4) void gemm_bt(
    const short* __restrict__ A, const short* __restrict__ BT, int N,
    const float* __restrict__ bias, const float* __restrict__ residF,
    const short* __restrict__ residH,
    float* __restrict__ outF, short* __restrict__ outH,
    short* __restrict__ qO, short* __restrict__ kO, short* __restrict__ vtO)
{
    const int tid = threadIdx.x, lane = tid & 63, w = tid >> 6;
    const int wm = w >> 1, wn = w & 1;
    const int mi = lane & 15, quad = lane >> 4;
    const int lid = blockIdx.x + gridDim.x * blockIdx.y;
    const int xcd = lid & 7, i8 = lid >> 3;
    const int rowBase = (xcd * 8 + (i8 & 7)) * 128;
    const int colBase = (i8 >> 3) * 128;

    __shared__ alignas(16) short As[2][128 * 32];
    __shared__ alignas(16) short Bs[2][128 * 32];

    const floatx4 z4 = {0.f, 0.f, 0.f, 0.f};
    floatx4 acc[4][4];
    #pragma unroll
    for (int i = 0; i < 4; ++i)
        #pragma unroll
        for (int j = 0; j < 4; ++j) acc[i][j] = z4;

    auto stage = [&](int k0, int buf) {
        #pragma unroll
        for (int i = 0; i < 2; ++i) {
            const int cb = i * 256 + w * 64;      // wave-uniform chunk base
            const int chunk = cb + lane;
            const int r = chunk >> 2, cc = chunk & 3;
            const int csw = cc ^ ((r >> 1) & 3);  // source-chunk swizzle
            load_lds16(A + (size_t)(rowBase + r) * KDIM + k0 + csw * 8,
                       (char*)As[buf] + cb * 16);
            load_lds16(BT + (size_t)(colBase + r) * KDIM + k0 + csw * 8,
                       (char*)Bs[buf] + cb * 16);
        }
    };

    auto compute = [&](const short* Ac, const short* Bc) {
        bf16x8 af[4], bfv[4];
        #pragma unroll
        for (int it = 0; it < 4; ++it) {
            const int ra = wm * 64 + it * 16 + mi;
            af[it] = *(const bf16x8*)(Ac + ra * 32 + ((quad ^ ((ra >> 1) & 3)) << 3));
        }
        #pragma unroll
        for (int jt = 0; jt < 4; ++jt) {
            const int rb = wn * 64 + jt * 16 + mi;
            bfv[jt] = *(const bf16x8*)(Bc + rb * 32 + ((quad ^ ((rb >> 1) & 3)) << 3));
        }
        #pragma unroll
        for (int it = 0; it < 4; ++it)
            #pragma unroll
            for (int jt = 0; jt < 4; ++jt) {
                if constexpr (SWAP)
                    acc[it][jt] = mfma16(bfv[jt], af[it], acc[it][jt]);
                else
                    acc[it][jt] = mfma16(af[it], bfv[jt], acc[it][jt]);
            }
    };

    stage(0, 0);
    #pragma unroll 1
    for (int c = 0; c < KDIM / 32; c += 2) {
        __syncthreads();                          // drains stage(c) into buf0
        if (c + 1 < KDIM / 32) stage((c + 1) * 32, 1);
        compute(As[0], Bs[0]);
        __syncthreads();                          // drains stage(c+1) into buf1
        if (c + 2 < KDIM / 32) stage((c + 2) * 32, 0);
        compute(As[1], Bs[1]);
    }

    if constexpr (SWAP) {
        // lane -> row = ...+mi ; registers -> 4 consecutive cols (quad*4+r)
        #pragma unroll
        for (int it = 0; it < 4; ++it) {
            const int row = rowBase + wm * 64 + it * 16 + mi;
            #pragma unroll
            for (int jt = 0; jt < 4; ++jt) {
                const int col0 = colBase + wn * 64 + jt * 16 + quad * 4;
                const floatx4 a4 = acc[it][jt];
                if constexpr (EPI == 0) {
                    if (colBase < 1024) {
                        const float qs = 0.18033688011112042f;  // 0.125*log2(e)
                        *(uint2*)(qO + (size_t)row * 1024 + col0) =
                            make_uint2(pk2bf(a4[0] * qs, a4[1] * qs),
                                       pk2bf(a4[2] * qs, a4[3] * qs));
                    } else {
                        *(uint2*)(kO + (size_t)row * 1024 + (col0 - 1024)) =
                            make_uint2(pk2bf(a4[0], a4[1]), pk2bf(a4[2], a4[3]));
                    }
                } else if constexpr (EPI == 2) {
                    const float4 b4 = *(const float4*)(bias + col0);
                    *(uint2*)(outH + (size_t)row * N + col0) =
                        make_uint2(pk2bf(fmaxf(a4[0] + b4.x, 0.f), fmaxf(a4[1] + b4.y, 0.f)),
                                   pk2bf(fmaxf(a4[2] + b4.z, 0.f), fmaxf(a4[3] + b4.w, 0.f)));
                } else if constexpr (EPI == 4) {
                    const float4 b4 = *(const float4*)(bias + col0);
                    const float4 r4 = *(const float4*)(residF + (size_t)row * N + col0);
                    *(uint2*)(outH + (size_t)row * N + col0) =
                        make_uint2(pk2bf(a4[0] + b4.x + r4.x, a4[1] + b4.y + r4.y),
                                   pk2bf(a4[2] + b4.z + r4.z, a4[3] + b4.w + r4.w));
                } else {  // EPI == 5
                    const float4 b4 = *(const float4*)(bias + col0);
                    const short4 r4 = *(const short4*)(residH + (size_t)row * N + col0);
                    float4 o;
                    o.x = a4[0] + b4.x + bf2f(r4.x);
                    o.y = a4[1] + b4.y + bf2f(r4.y);
                    o.z = a4[2] + b4.z + bf2f(r4.z);
                    o.w = a4[3] + b4.w + bf2f(r4.w);
                    *(float4*)(outF + (size_t)row * N + col0) = o;
                }
            }
        }
    } else {
        // EPI 3: V transposed. lane -> weight col c ; registers -> 4 consecutive t
        #pragma unroll
        for (int it = 0; it < 4; ++it) {
            const int row0 = rowBase + wm * 64 + it * 16 + quad * 4;
            const int bb = row0 >> 10, t0 = row0 & 1023;
            #pragma unroll
            for (int jt = 0; jt < 4; ++jt) {
                const int c = colBase + wn * 64 + jt * 16 + mi;
                const floatx4 a4 = acc[it][jt];
                *(uint2*)(vtO + ((size_t)bb << 20) + ((size_t)c << 10) + t0) =
                    make_uint2(pk2bf(a4[0], a4[1]), pk2bf(a4[2], a4[3]));
            }
        }
    }
}

// ---------------- Flash attention (causal), bf16 MFMA ----------------
// Triangle-balanced: block owns q-tiles pi and 15-pi; K/V staged once per
// s-tile, applied to both q-tiles.  XCD-remapped 1D grid (1024 blocks).
// Q pre-scaled by 0.125*log2(e) -> p = 2^s via raw v_exp_f32 (1 VALU).
#define PSTR 88   // P row stride in shorts (176 B: 16B-aligned)
__device__ __forceinline__ void attn_qk_pv(
    const bf16x8 qf0, const bf16x8 qf1,
    floatx4 (&o)[4], float (&lsum)[4],
    const short* Ks, const short* Vs, short* myP,
    const int mi, const int quad, const int kq, const int diagRowOff)
{
    const floatx4 z4 = {0.f, 0.f, 0.f, 0.f};
    const bool diag = diagRowOff >= 0;
    floatx4 sa[4];
    #pragma unroll
    for (int j = 0; j < 4; ++j) {
        const int row = j * 16 + mi;
        const int sw = row & 7;
        floatx4 s4 = z4;
        s4 = mfma16(qf0, *(const bf16x8*)(Ks + row * 64 + ((quad ^ sw) << 3)), s4);
        s4 = mfma16(qf1, *(const bf16x8*)(Ks + row * 64 + (((quad + 4) ^ sw) << 3)), s4);
        sa[j] = s4;
    }
    #pragma unroll
    for (int j = 0; j < 4; ++j) {
        float p[4];
        #pragma unroll
        for (int r = 0; r < 4; ++r) {
            p[r] = exp2_hw(sa[j][r]);
            if (diag && (j * 16 + mi > diagRowOff + quad * 4 + r)) p[r] = 0.f;
            lsum[r] += p[r];
        }
        const unsigned ua = pk2bf(p[0], p[1]);
        const unsigned ub = pk2bf(p[2], p[3]);
        myP[(quad * 4 + 0) * PSTR + j * 16 + mi] = (short)ua;
        myP[(quad * 4 + 1) * PSTR + j * 16 + mi] = (short)(ua >> 16);
        myP[(quad * 4 + 2) * PSTR + j * 16 + mi] = (short)ub;
        myP[(quad * 4 + 3) * PSTR + j * 16 + mi] = (short)(ub >> 16);
    }
    __asm__ volatile("s_waitcnt lgkmcnt(0)" ::: "memory");
    const bf16x8 pf0 = *(const bf16x8*)(myP + mi * PSTR + kq);
    const bf16x8 pf1 = *(const bf16x8*)(myP + mi * PSTR + 32 + kq);
    #pragma unroll
    for (int d = 0; d < 4; ++d) {
        const int row = d * 16 + mi;
        const int sw = row & 7;
        o[d] = mfma16(pf0, *(const bf16x8*)(Vs + row * 64 + ((quad ^ sw) << 3)), o[d]);
        o[d] = mfma16(pf1, *(const bf16x8*)(Vs + row * 64 + (((quad + 4) ^ sw) << 3)), o[d]);
    }
}

__global__ __launch_bounds__(256, 4) void flash_attn(
    const short* __restrict__ Q, const short* __restrict__ K,
    const short* __restrict__ Vt, short* __restrict__ O)
{
    const int tid = threadIdx.x, lane = tid & 63, w = tid >> 6;
    const int mi = lane & 15, quad = lane >> 4, kq = quad * 8;
    const int lid = blockIdx.x;
    const int xcd = lid & 7, i8 = lid >> 3;
    const int bh = xcd * 16 + (i8 & 15);
    const int pi = i8 >> 4;
    const int h = bh & 15, b = bh >> 4;
    const int tA = pi, tB = 15 - pi;
    const int qbA = tA * 64, qbB = tB * 64;

    __shared__ alignas(16) short Ks[64 * 64];       // [s][d] swizzled, 8 KB
    __shared__ alignas(16) short Vs[64 * 64];       // [d][s] swizzled, 8 KB
    __shared__ alignas(16) short Ps[4][16 * PSTR];  // per-wave P

    const size_t qoffA = ((size_t)(b * 1024 + qbA + w * 16 + mi)) * 1024 + h * 64;
    const size_t qoffB = ((size_t)(b * 1024 + qbB + w * 16 + mi)) * 1024 + h * 64;
    const bf16x8 qA0 = *(const bf16x8*)(Q + qoffA + kq);
    const bf16x8 qA1 = *(const bf16x8*)(Q + qoffA + 32 + kq);
    const bf16x8 qB0 = *(const bf16x8*)(Q + qoffB + kq);
    const bf16x8 qB1 = *(const bf16x8*)(Q + qoffB + 32 + kq);

    const floatx4 z4 = {0.f, 0.f, 0.f, 0.f};
    floatx4 oA[4], oB[4];
    float lA[4], lB[4];
    #pragma unroll
    for (int i = 0; i < 4; ++i) { oA[i] = z4; oB[i] = z4; lA[i] = 0.f; lB[i] = 0.f; }

    short* myP = &Ps[w][0];
    for (int t = 0; t <= tB; ++t) {
        const int s0 = t * 64;
        __syncthreads();
        #pragma unroll
        for (int i = 0; i < 2; ++i) {
            const int cb = i * 256 + w * 64;       // wave-uniform chunk base
            const int chunk = cb + lane;
            const int r = chunk >> 3, c = chunk & 7;
            const int csw = c ^ (r & 7);           // swizzle: slot(r,c) <- chunk c^(r&7)
            load_lds16(K + ((size_t)(b * 1024 + s0 + r)) * 1024 + h * 64 + csw * 8,
                       (char*)Ks + cb * 16);
            load_lds16(Vt + ((size_t)b << 20) + ((size_t)(h * 64 + r) << 10) + s0 + csw * 8,
                       (char*)Vs + cb * 16);
        }
        __syncthreads();

        if (t <= tA)
            attn_qk_pv(qA0, qA1, oA, lA, Ks, Vs, myP, mi, quad, kq,
                       (t == tA) ? (w * 16) : -1);
        attn_qk_pv(qB0, qB1, oB, lB, Ks, Vs, myP, mi, quad, kq,
                   (t == tB) ? (w * 16) : -1);
    }

    #pragma unroll
    for (int r = 0; r < 4; ++r) {
        float sA = lA[r], sB = lB[r];
        #pragma unroll
        for (int off = 1; off < 16; off <<= 1) {
            sA += __shfl_xor(sA, off);
            sB += __shfl_xor(sB, off);
        }
        lA[r] = 1.0f / sA;
        lB[r] = 1.0f / sB;
    }
    #pragma unroll
    for (int d = 0; d < 4; ++d)
        #pragma unroll
        for (int r = 0; r < 4; ++r) {
            const int col = h * 64 + d * 16 + mi;
            const int rowA = b * 1024 + qbA + w * 16 + quad * 4 + r;
            const int rowB = b * 1024 + qbB + w * 16 + quad * 4 + r;
            O[(size_t)rowA * 1024 + col] = f2bf(oA[d][r] * lA[r]);
            O[(size_t)rowB * 1024 + col] = f2bf(oB[d][r] * lB[r]);
        }
}

// ---------------- host launcher ----------------
extern "C" void kernel_launch(void* const* d_in, const int* in_sizes, int n_in,
                              void* d_out, int out_size, void* d_ws, size_t ws_size,
                              hipStream_t stream)
{
    (void)in_sizes; (void)n_in; (void)out_size; (void)ws_size;
    const float* x     = (const float*)d_in[0];
    const float* Wq    = (const float*)d_in[1];
    const float* Wk    = (const float*)d_in[2];
    const float* Wv    = (const float*)d_in[3];
    const float* Wproj = (const float*)d_in[4];
    const float* bproj = (const float*)d_in[5];
    const float* W1    = (const float*)d_in[6];
    const float* b1    = (const float*)d_in[7];
    const float* W2    = (const float*)d_in[8];
    const float* b2    = (const float*)d_in[9];
    const float* g1    = (const float*)d_in[10];
    const float* be1   = (const float*)d_in[11];
    const float* g2    = (const float*)d_in[12];
    const float* be2   = (const float*)d_in[13];
    float* out = (float*)d_out;

    char* ws = (char*)d_ws;
    const size_t MB = 1u << 20;
    short* Qb     = (short*)(ws + 0 * MB);    // 16 MB  [8192][1024] bf16
    short* Kb     = (short*)(ws + 16 * MB);   // 16 MB  [8192][1024] bf16
    short* Vtb    = (short*)(ws + 32 * MB);   // 16 MB  [B][C][T] bf16
    short* XN     = (short*)(ws + 48 * MB);   // 16 MB  xn then xn2
    short* AT     = (short*)(ws + 64 * MB);   // 16 MB  attn then h
    short* R2b    = (short*)(ws + 80 * MB);   // 16 MB  resid2 bf16
    short* WqkvT  = (short*)(ws + 112 * MB);  // 6 MB
    short* WprojT = (short*)(ws + 118 * MB);  // 2 MB
    short* W1T    = (short*)(ws + 120 * MB);  // 2 MB
    short* W2T    = (short*)(ws + 122 * MB);  // 2 MB

    pack_all<<<dim3(192, 32), dim3(32, 8), 0, stream>>>(
        Wq, Wk, Wv, Wproj, W1, W2, WqkvT, WprojT, W1T, W2T);

    ln_kernel<false><<<8192, 256, 0, stream>>>(x, g1, be1, XN);

    // QK part (cols 0..2047 of WqkvT), swapped-operand epilogue
    gemm_bt<0, true><<<dim3(16, 64), 256, 0, stream>>>(XN, WqkvT, 1024,
        nullptr, nullptr, nullptr, nullptr, nullptr, Qb, Kb, nullptr);
    // V part (cols 2048..3071), normal order -> transposed store
    gemm_bt<3, false><<<dim3(8, 64), 256, 0, stream>>>(XN, WqkvT + 2048 * KDIM, 1024,
        nullptr, nullptr, nullptr, nullptr, nullptr, nullptr, nullptr, Vtb);

    flash_attn<<<1024, 256, 0, stream>>>(Qb, Kb, Vtb, AT);

    // proj: R2b (bf16) = attn @ Wproj + bproj + x
    gemm_bt<4, true><<<dim3(8, 64), 256, 0, stream>>>(AT, WprojT, 1024,
        bproj, x, nullptr, nullptr, R2b, nullptr, nullptr, nullptr);

    ln_kernel<true><<<8192, 256, 0, stream>>>(R2b, g2, be2, XN);

    gemm_bt<2, true><<<dim3(8, 64), 256, 0, stream>>>(XN, W1T, 1024,
        b1, nullptr, nullptr, nullptr, AT, nullptr, nullptr, nullptr);

    // out (fp32) = h @ W2 + b2 + R2b
    gemm_bt<5, true><<<dim3(8, 64), 256, 0, stream>>>(AT, W2T, 1024,
        b2, nullptr, R2b, out, nullptr, nullptr, nullptr, nullptr);
}

// Round 8
// 305.954 us; speedup vs baseline: 1.1028x; 1.0288x over previous
//
#include <hip/hip_runtime.h>
#include <hip/hip_bf16.h>

// ---- constants for this problem ----
// B=8, T=1024, C=1024, H=16, Dh=64 ; M = B*T = 8192, K = C = 1024
#define KDIM 1024

typedef __bf16  bf16x8  __attribute__((ext_vector_type(8)));
typedef float   floatx4 __attribute__((ext_vector_type(4)));

__device__ inline short f2bf(float f) {
    unsigned u = __float_as_uint(f);
    u += 0x7fffu + ((u >> 16) & 1u);     // round-to-nearest-even
    return (short)(u >> 16);
}
__device__ inline float bf2f(short s) {
    return __uint_as_float(((unsigned)(unsigned short)s) << 16);
}
// packed f32x2 -> bf16x2 (v_cvt_pk_bf16_f32)
__device__ inline unsigned pk2bf(float x, float y) {
    __hip_bfloat162 h = __float22bfloat162_rn(make_float2(x, y));
    return *reinterpret_cast<unsigned*>(&h);
}
// raw v_exp_f32: computes 2^x in one VALU op
__device__ inline float exp2_hw(float x) {
    float r;
    __asm__("v_exp_f32 %0, %1" : "=v"(r) : "v"(x));
    return r;
}

__device__ inline floatx4 mfma16(bf16x8 a, bf16x8 b, floatx4 c) {
    return __builtin_amdgcn_mfma_f32_16x16x32_bf16(a, b, c, 0, 0, 0);
}

// async global->LDS, 16B per lane.  lds pointer must be wave-uniform base;
// HW adds lane*16.
__device__ inline void load_lds16(const void* g, void* l) {
    __builtin_amdgcn_global_load_lds(
        (__attribute__((address_space(1))) void*)(unsigned long long)g,
        (__attribute__((address_space(3))) void*)(unsigned)(unsigned long long)l,
        16, 0, 0);
}

// ---------------- LayerNorm body (one 256-thread block per row) ----------------
template <bool BF16IN>
__device__ __forceinline__ void ln_body(
    const void* __restrict__ xv, const float* __restrict__ g,
    const float* __restrict__ be, short* __restrict__ out,
    const int row, const int tid)
{
    float4 v;
    if constexpr (BF16IN) {
        const short4 s4 = ((const short4*)xv)[(size_t)row * 256 + tid];
        v.x = bf2f(s4.x); v.y = bf2f(s4.y); v.z = bf2f(s4.z); v.w = bf2f(s4.w);
    } else {
        v = ((const float4*)xv)[(size_t)row * 256 + tid];
    }
    float s  = v.x + v.y + v.z + v.w;
    float s2 = v.x * v.x + v.y * v.y + v.z * v.z + v.w * v.w;
    #pragma unroll
    for (int off = 32; off; off >>= 1) {
        s  += __shfl_down(s, off);
        s2 += __shfl_down(s2, off);
    }
    __shared__ float red1[4], red2[4];
    const int w = tid >> 6, lane = tid & 63;
    if (lane == 0) { red1[w] = s; red2[w] = s2; }
    __syncthreads();
    s  = red1[0] + red1[1] + red1[2] + red1[3];
    s2 = red2[0] + red2[1] + red2[2] + red2[3];
    const float mean = s * (1.0f / 1024.0f);
    const float var  = s2 * (1.0f / 1024.0f) - mean * mean;
    const float rstd = rsqrtf(var + 1e-5f);
    const float4 gg = ((const float4*)g)[tid];
    const float4 bb = ((const float4*)be)[tid];
    const unsigned o01 = pk2bf((v.x - mean) * rstd * gg.x + bb.x,
                               (v.y - mean) * rstd * gg.y + bb.y);
    const unsigned o23 = pk2bf((v.z - mean) * rstd * gg.z + bb.z,
                               (v.w - mean) * rstd * gg.w + bb.w);
    *(uint2*)(out + (size_t)row * 1024 + tid * 4) = make_uint2(o01, o23);
}

__global__ __launch_bounds__(256) void ln_kernel_bf16(
    const short* __restrict__ xv, const float* __restrict__ g,
    const float* __restrict__ be, short* __restrict__ out)
{
    ln_body<true>(xv, g, be, out, blockIdx.x, threadIdx.x);
}

// -------- pre-kernel: LN1 (blocks 0..8191) + all weight packs (rest) --------
__global__ __launch_bounds__(256) void pre_kernel(
    const float* __restrict__ x, const float* __restrict__ g1,
    const float* __restrict__ be1, short* __restrict__ XN,
    const float* __restrict__ Wq, const float* __restrict__ Wk,
    const float* __restrict__ Wv, const float* __restrict__ Wproj,
    const float* __restrict__ W1, const float* __restrict__ W2,
    short* __restrict__ qkvT, short* __restrict__ projT,
    short* __restrict__ w1T, short* __restrict__ w2T)
{
    const int id = blockIdx.x, tid = threadIdx.x;
    if (id < 8192) {
        ln_body<false>(x, g1, be1, XN, id, tid);
        return;
    }
    __shared__ float tile[32][33];
    const int pidx = id - 8192;            // 0..6143 = 192 x 32
    const int bx = pidx % 192, c0 = (pidx / 192) * 32;
    const int tx = tid & 31, ty = tid >> 5;   // 32 x 8
    if (bx < 96) {
        const int n0 = bx * 32;
        const int grp = n0 >> 10;
        const float* W = (grp == 0) ? Wq : (grp == 1 ? Wk : Wv);
        const int nb = n0 & 1023, hh = nb >> 6, d0 = nb & 63;
        #pragma unroll
        for (int j = 0; j < 32; j += 8)
            tile[ty + j][tx] = W[hh * 65536 + (c0 + ty + j) * 64 + d0 + tx];
        __syncthreads();
        #pragma unroll
        for (int j = 0; j < 32; j += 8)
            qkvT[(size_t)(n0 + ty + j) * 1024 + c0 + tx] = f2bf(tile[tx][ty + j]);
    } else {
        const int which = (bx - 96) >> 5;
        const int n0 = ((bx - 96) & 31) * 32;
        const float* src = (which == 0) ? Wproj : (which == 1 ? W1 : W2);
        short* dst = (which == 0) ? projT : (which == 1 ? w1T : w2T);
        #pragma unroll
        for (int j = 0; j < 32; j += 8)
            tile[ty + j][tx] = src[(size_t)(c0 + ty + j) * 1024 + n0 + tx];
        __syncthreads();
        #pragma unroll
        for (int j = 0; j < 32; j += 8)
            dst[(size_t)(n0 + ty + j) * 1024 + c0 + tx] = f2bf(tile[tx][ty + j]);
    }
}

// ---------------- shared GEMM K-loop ----------------
// 128x128 tile, WAVES waves (4 or 8), BK=32, single-barrier double-buffered:
// barrier -> issue async stage of chunk c+1 -> compute chunk c.
// XOR-swizzled LDS -> conflict-free ds_read_b128.
// SWAP: mfma(B,A) -> C/D register axis = output COLUMN.
template <bool SWAP, int WAVES, int IT>
__device__ __forceinline__ void kloop(
    const short* __restrict__ A, const short* __restrict__ BT,
    short (&As)[2][128 * 32], short (&Bs)[2][128 * 32],
    floatx4 (&acc)[IT][4], const int rowBase, const int colBase,
    const int w, const int lane, const int mi, const int quad)
{
    const int wm = w >> 1, wn = w & 1;
    auto stage = [&](int k0, int buf) {
        #pragma unroll
        for (int i = 0; i < 512 / (WAVES * 64); ++i) {
            const int cb = i * (WAVES * 64) + w * 64;   // wave-uniform chunk base
            const int chunk = cb + lane;
            const int r = chunk >> 2, cc = chunk & 3;
            const int csw = cc ^ ((r >> 1) & 3);        // source-chunk swizzle
            load_lds16(A + (size_t)(rowBase + r) * KDIM + k0 + csw * 8,
                       (char*)As[buf] + cb * 16);
            load_lds16(BT + (size_t)(colBase + r) * KDIM + k0 + csw * 8,
                       (char*)Bs[buf] + cb * 16);
        }
    };
    auto compute = [&](const short* Ac, const short* Bc) {
        bf16x8 af[IT], bfv[4];
        #pragma unroll
        for (int it = 0; it < IT; ++it) {
            const int ra = wm * (IT * 16) + it * 16 + mi;
            af[it] = *(const bf16x8*)(Ac + ra * 32 + ((quad ^ ((ra >> 1) & 3)) << 3));
        }
        #pragma unroll
        for (int jt = 0; jt < 4; ++jt) {
            const int rb = wn * 64 + jt * 16 + mi;
            bfv[jt] = *(const bf16x8*)(Bc + rb * 32 + ((quad ^ ((rb >> 1) & 3)) << 3));
        }
        #pragma unroll
        for (int it = 0; it < IT; ++it)
            #pragma unroll
            for (int jt = 0; jt < 4; ++jt) {
                if constexpr (SWAP)
                    acc[it][jt] = mfma16(bfv[jt], af[it], acc[it][jt]);
                else
                    acc[it][jt] = mfma16(af[it], bfv[jt], acc[it][jt]);
            }
    };
    stage(0, 0);
    #pragma unroll 1
    for (int c = 0; c < KDIM / 32; c += 2) {
        __syncthreads();                          // drains stage(c) into buf0
        if (c + 1 < KDIM / 32) stage((c + 1) * 32, 1);
        compute(As[0], Bs[0]);
        __syncthreads();                          // drains stage(c+1) into buf1
        if (c + 2 < KDIM / 32) stage((c + 2) * 32, 0);
        compute(As[1], Bs[1]);
    }
}

// ---------------- fused QKV GEMM: [8192,1024] x [3072,1024]^T ----------------
// 1536 blocks, 4 waves.  colBase<2048: SWAP path -> Q (scaled) / K row-major.
// colBase>=2048: noswap path -> V transposed scatter (regs = 4 consecutive t).
__global__ __launch_bounds__(256, 4) void gemm_qkv(
    const short* __restrict__ XN, const short* __restrict__ WT,
    short* __restrict__ qO, short* __restrict__ kO, short* __restrict__ vtO)
{
    const int tid = threadIdx.x, lane = tid & 63, w = tid >> 6;
    const int mi = lane & 15, quad = lane >> 4;
    const int lid = blockIdx.x;
    const int xcd = lid & 7, i8 = lid >> 3;
    const int rowBase = (xcd * 8 + (i8 & 7)) * 128;
    const int colBase = (i8 >> 3) * 128;            // 0..2944

    __shared__ alignas(16) short As[2][128 * 32];
    __shared__ alignas(16) short Bs[2][128 * 32];

    const floatx4 z4 = {0.f, 0.f, 0.f, 0.f};
    const int wm = w >> 1, wn = w & 1;

    if (colBase < 2048) {
        floatx4 acc[4][4];
        #pragma unroll
        for (int i = 0; i < 4; ++i)
            #pragma unroll
            for (int j = 0; j < 4; ++j) acc[i][j] = z4;
        kloop<true, 4, 4>(XN, WT, As, Bs, acc, rowBase, colBase, w, lane, mi, quad);
        #pragma unroll
        for (int it = 0; it < 4; ++it) {
            const int row = rowBase + wm * 64 + it * 16 + mi;
            #pragma unroll
            for (int jt = 0; jt < 4; ++jt) {
                const int col0 = colBase + wn * 64 + jt * 16 + quad * 4;
                const floatx4 a4 = acc[it][jt];
                if (colBase < 1024) {
                    const float qs = 0.18033688011112042f;  // 0.125*log2(e)
                    *(uint2*)(qO + (size_t)row * 1024 + col0) =
                        make_uint2(pk2bf(a4[0] * qs, a4[1] * qs),
                                   pk2bf(a4[2] * qs, a4[3] * qs));
                } else {
                    *(uint2*)(kO + (size_t)row * 1024 + (col0 - 1024)) =
                        make_uint2(pk2bf(a4[0], a4[1]), pk2bf(a4[2], a4[3]));
                }
            }
        }
    } else {
        floatx4 acc[4][4];
        #pragma unroll
        for (int i = 0; i < 4; ++i)
            #pragma unroll
            for (int j = 0; j < 4; ++j) acc[i][j] = z4;
        kloop<false, 4, 4>(XN, WT, As, Bs, acc, rowBase, colBase, w, lane, mi, quad);
        #pragma unroll
        for (int it = 0; it < 4; ++it) {
            const int row0 = rowBase + wm * 64 + it * 16 + quad * 4;
            const int bb = row0 >> 10, t0 = row0 & 1023;
            #pragma unroll
            for (int jt = 0; jt < 4; ++jt) {
                const int c = (colBase - 2048) + wn * 64 + jt * 16 + mi;
                const floatx4 a4 = acc[it][jt];
                *(uint2*)(vtO + ((size_t)bb << 20) + ((size_t)c << 10) + t0) =
                    make_uint2(pk2bf(a4[0], a4[1]), pk2bf(a4[2], a4[3]));
            }
        }
    }
}

// ---------------- N=1024 GEMMs: 512 blocks x 8 waves (16 waves/CU) ----------
// EPI 2: relu bf16 + bias   EPI 4: bf16 = acc+bias+residF32
// EPI 5: f32 = acc+bias+residBf16
template <int EPI>
__global__ __launch_bounds__(512, 2) void gemm_n1024(
    const short* __restrict__ A, const short* __restrict__ BT,
    const float* __restrict__ bias, const float* __restrict__ residF,
    const short* __restrict__ residH,
    float* __restrict__ outF, short* __restrict__ outH)
{
    const int tid = threadIdx.x, lane = tid & 63, w = tid >> 6;   // w 0..7
    const int mi = lane & 15, quad = lane >> 4;
    const int lid = blockIdx.x;
    const int xcd = lid & 7, i8 = lid >> 3;
    const int rowBase = (xcd * 8 + (i8 & 7)) * 128;
    const int colBase = (i8 >> 3) * 128;

    __shared__ alignas(16) short As[2][128 * 32];
    __shared__ alignas(16) short Bs[2][128 * 32];

    const floatx4 z4 = {0.f, 0.f, 0.f, 0.f};
    floatx4 acc[2][4];
    #pragma unroll
    for (int i = 0; i < 2; ++i)
        #pragma unroll
        for (int j = 0; j < 4; ++j) acc[i][j] = z4;

    kloop<true, 8, 2>(A, BT, As, Bs, acc, rowBase, colBase, w, lane, mi, quad);

    const int wm = w >> 1, wn = w & 1;   // wm 0..3 (32-row slices), wn 0..1
    #pragma unroll
    for (int it = 0; it < 2; ++it) {
        const int row = rowBase + wm * 32 + it * 16 + mi;
        #pragma unroll
        for (int jt = 0; jt < 4; ++jt) {
            const int col0 = colBase + wn * 64 + jt * 16 + quad * 4;
            const floatx4 a4 = acc[it][jt];
            if constexpr (EPI == 2) {
                const float4 b4 = *(const float4*)(bias + col0);
                *(uint2*)(outH + (size_t)row * 1024 + col0) =
                    make_uint2(pk2bf(fmaxf(a4[0] + b4.x, 0.f), fmaxf(a4[1] + b4.y, 0.f)),
                               pk2bf(fmaxf(a4[2] + b4.z, 0.f), fmaxf(a4[3] + b4.w, 0.f)));
            } else if constexpr (EPI == 4) {
                const float4 b4 = *(const float4*)(bias + col0);
                const float4 r4 = *(const float4*)(residF + (size_t)row * 1024 + col0);
                *(uint2*)(outH + (size_t)row * 1024 + col0) =
                    make_uint2(pk2bf(a4[0] + b4.x + r4.x, a4[1] + b4.y + r4.y),
                               pk2bf(a4[2] + b4.z + r4.z, a4[3] + b4.w + r4.w));
            } else {  // EPI == 5
                const float4 b4 = *(const float4*)(bias + col0);
                const short4 r4 = *(const short4*)(residH + (size_t)row * 1024 + col0);
                float4 o;
                o.x = a4[0] + b4.x + bf2f(r4.x);
                o.y = a4[1] + b4.y + bf2f(r4.y);
                o.z = a4[2] + b4.z + bf2f(r4.z);
                o.w = a4[3] + b4.w + bf2f(r4.w);
                *(float4*)(outF + (size_t)row * 1024 + col0) = o;
            }
        }
    }
}

// ---------------- Flash attention (causal), bf16 MFMA ----------------
// Triangle-balanced: block owns q-tiles pi and 15-pi; K/V staged once per
// s-tile, applied to both q-tiles.  XCD-remapped 1D grid (1024 blocks).
// Q pre-scaled by 0.125*log2(e) -> p = 2^s via raw v_exp_f32 (1 VALU).
#define PSTR 88   // P row stride in shorts (176 B: 16B-aligned)
__device__ __forceinline__ void attn_qk_pv(
    const bf16x8 qf0, const bf16x8 qf1,
    floatx4 (&o)[4], float (&lsum)[4],
    const short* Ks, const short* Vs, short* myP,
    const int mi, const int quad, const int kq, const int diagRowOff)
{
    const floatx4 z4 = {0.f, 0.f, 0.f, 0.f};
    const bool diag = diagRowOff >= 0;
    floatx4 sa[4];
    #pragma unroll
    for (int j = 0; j < 4; ++j) {
        const int row = j * 16 + mi;
        const int sw = row & 7;
        floatx4 s4 = z4;
        s4 = mfma16(qf0, *(const bf16x8*)(Ks + row * 64 + ((quad ^ sw) << 3)), s4);
        s4 = mfma16(qf1, *(const bf16x8*)(Ks + row * 64 + (((quad + 4) ^ sw) << 3)), s4);
        sa[j] = s4;
    }
    #pragma unroll
    for (int j = 0; j < 4; ++j) {
        float p[4];
        #pragma unroll
        for (int r = 0; r < 4; ++r) {
            p[r] = exp2_hw(sa[j][r]);
            if (diag && (j * 16 + mi > diagRowOff + quad * 4 + r)) p[r] = 0.f;
            lsum[r] += p[r];
        }
        const unsigned ua = pk2bf(p[0], p[1]);
        const unsigned ub = pk2bf(p[2], p[3]);
        myP[(quad * 4 + 0) * PSTR + j * 16 + mi] = (short)ua;
        myP[(quad * 4 + 1) * PSTR + j * 16 + mi] = (short)(ua >> 16);
        myP[(quad * 4 + 2) * PSTR + j * 16 + mi] = (short)ub;
        myP[(quad * 4 + 3) * PSTR + j * 16 + mi] = (short)(ub >> 16);
    }
    __asm__ volatile("s_waitcnt lgkmcnt(0)" ::: "memory");
    const bf16x8 pf0 = *(const bf16x8*)(myP + mi * PSTR + kq);
    const bf16x8 pf1 = *(const bf16x8*)(myP + mi * PSTR + 32 + kq);
    #pragma unroll
    for (int d = 0; d < 4; ++d) {
        const int row = d * 16 + mi;
        const int sw = row & 7;
        o[d] = mfma16(pf0, *(const bf16x8*)(Vs + row * 64 + ((quad ^ sw) << 3)), o[d]);
        o[d] = mfma16(pf1, *(const bf16x8*)(Vs + row * 64 + (((quad + 4) ^ sw) << 3)), o[d]);
    }
}

__global__ __launch_bounds__(256, 4) void flash_attn(
    const short* __restrict__ Q, const short* __restrict__ K,
    const short* __restrict__ Vt, short* __restrict__ O)
{
    const int tid = threadIdx.x, lane = tid & 63, w = tid >> 6;
    const int mi = lane & 15, quad = lane >> 4, kq = quad * 8;
    const int lid = blockIdx.x;
    const int xcd = lid & 7, i8 = lid >> 3;
    const int bh = xcd * 16 + (i8 & 15);
    const int pi = i8 >> 4;
    const int h = bh & 15, b = bh >> 4;
    const int tA = pi, tB = 15 - pi;
    const int qbA = tA * 64, qbB = tB * 64;

    __shared__ alignas(16) short Ks[64 * 64];       // [s][d] swizzled, 8 KB
    __shared__ alignas(16) short Vs[64 * 64];       // [d][s] swizzled, 8 KB
    __shared__ alignas(16) short Ps[4][16 * PSTR];  // per-wave P

    const size_t qoffA = ((size_t)(b * 1024 + qbA + w * 16 + mi)) * 1024 + h * 64;
    const size_t qoffB = ((size_t)(b * 1024 + qbB + w * 16 + mi)) * 1024 + h * 64;
    const bf16x8 qA0 = *(const bf16x8*)(Q + qoffA + kq);
    const bf16x8 qA1 = *(const bf16x8*)(Q + qoffA + 32 + kq);
    const bf16x8 qB0 = *(const bf16x8*)(Q + qoffB + kq);
    const bf16x8 qB1 = *(const bf16x8*)(Q + qoffB + 32 + kq);

    const floatx4 z4 = {0.f, 0.f, 0.f, 0.f};
    floatx4 oA[4], oB[4];
    float lA[4], lB[4];
    #pragma unroll
    for (int i = 0; i < 4; ++i) { oA[i] = z4; oB[i] = z4; lA[i] = 0.f; lB[i] = 0.f; }

    short* myP = &Ps[w][0];
    for (int t = 0; t <= tB; ++t) {
        const int s0 = t * 64;
        __syncthreads();
        #pragma unroll
        for (int i = 0; i < 2; ++i) {
            const int cb = i * 256 + w * 64;       // wave-uniform chunk base
            const int chunk = cb + lane;
            const int r = chunk >> 3, c = chunk & 7;
            const int csw = c ^ (r & 7);           // swizzle: slot(r,c) <- chunk c^(r&7)
            load_lds16(K + ((size_t)(b * 1024 + s0 + r)) * 1024 + h * 64 + csw * 8,
                       (char*)Ks + cb * 16);
            load_lds16(Vt + ((size_t)b << 20) + ((size_t)(h * 64 + r) << 10) + s0 + csw * 8,
                       (char*)Vs + cb * 16);
        }
        __syncthreads();

        if (t <= tA)
            attn_qk_pv(qA0, qA1, oA, lA, Ks, Vs, myP, mi, quad, kq,
                       (t == tA) ? (w * 16) : -1);
        attn_qk_pv(qB0, qB1, oB, lB, Ks, Vs, myP, mi, quad, kq,
                   (t == tB) ? (w * 16) : -1);
    }

    #pragma unroll
    for (int r = 0; r < 4; ++r) {
        float sA = lA[r], sB = lB[r];
        #pragma unroll
        for (int off = 1; off < 16; off <<= 1) {
            sA += __shfl_xor(sA, off);
            sB += __shfl_xor(sB, off);
        }
        lA[r] = 1.0f / sA;
        lB[r] = 1.0f / sB;
    }
    #pragma unroll
    for (int d = 0; d < 4; ++d)
        #pragma unroll
        for (int r = 0; r < 4; ++r) {
            const int col = h * 64 + d * 16 + mi;
            const int rowA = b * 1024 + qbA + w * 16 + quad * 4 + r;
            const int rowB = b * 1024 + qbB + w * 16 + quad * 4 + r;
            O[(size_t)rowA * 1024 + col] = f2bf(oA[d][r] * lA[r]);
            O[(size_t)rowB * 1024 + col] = f2bf(oB[d][r] * lB[r]);
        }
}

// ---------------- host launcher ----------------
extern "C" void kernel_launch(void* const* d_in, const int* in_sizes, int n_in,
                              void* d_out, int out_size, void* d_ws, size_t ws_size,
                              hipStream_t stream)
{
    (void)in_sizes; (void)n_in; (void)out_size; (void)ws_size;
    const float* x     = (const float*)d_in[0];
    const float* Wq    = (const float*)d_in[1];
    const float* Wk    = (const float*)d_in[2];
    const float* Wv    = (const float*)d_in[3];
    const float* Wproj = (const float*)d_in[4];
    const float* bproj = (const float*)d_in[5];
    const float* W1    = (const float*)d_in[6];
    const float* b1    = (const float*)d_in[7];
    const float* W2    = (const float*)d_in[8];
    const float* b2    = (const float*)d_in[9];
    const float* g1    = (const float*)d_in[10];
    const float* be1   = (const float*)d_in[11];
    const float* g2    = (const float*)d_in[12];
    const float* be2   = (const float*)d_in[13];
    float* out = (float*)d_out;

    char* ws = (char*)d_ws;
    const size_t MB = 1u << 20;
    short* Qb     = (short*)(ws + 0 * MB);    // 16 MB  [8192][1024] bf16
    short* Kb     = (short*)(ws + 16 * MB);   // 16 MB  [8192][1024] bf16
    short* Vtb    = (short*)(ws + 32 * MB);   // 16 MB  [B][C][T] bf16
    short* XN     = (short*)(ws + 48 * MB);   // 16 MB  xn then xn2
    short* AT     = (short*)(ws + 64 * MB);   // 16 MB  attn then h
    short* R2b    = (short*)(ws + 80 * MB);   // 16 MB  resid2 bf16
    short* WqkvT  = (short*)(ws + 112 * MB);  // 6 MB
    short* WprojT = (short*)(ws + 118 * MB);  // 2 MB
    short* W1T    = (short*)(ws + 120 * MB);  // 2 MB
    short* W2T    = (short*)(ws + 122 * MB);  // 2 MB

    // LN1 + all weight packs in one dispatch
    pre_kernel<<<8192 + 6144, 256, 0, stream>>>(
        x, g1, be1, XN, Wq, Wk, Wv, Wproj, W1, W2, WqkvT, WprojT, W1T, W2T);

    // fused QKV GEMM (Q scaled, K row-major, V transposed)
    gemm_qkv<<<1536, 256, 0, stream>>>(XN, WqkvT, Qb, Kb, Vtb);

    flash_attn<<<1024, 256, 0, stream>>>(Qb, Kb, Vtb, AT);

    // proj: R2b (bf16) = attn @ Wproj + bproj + x
    gemm_n1024<4><<<512, 512, 0, stream>>>(AT, WprojT, bproj, x, nullptr,
                                           nullptr, R2b);

    ln_kernel_bf16<<<8192, 256, 0, stream>>>(R2b, g2, be2, XN);

    // h = relu(xn2 @ W1 + b1)
    gemm_n1024<2><<<512, 512, 0, stream>>>(XN, W1T, b1, nullptr, nullptr,
                                           nullptr, AT);

    // out (fp32) = h @ W2 + b2 + R2b
    gemm_n1024<5><<<512, 512, 0, stream>>>(AT, W2T, b2, nullptr, R2b,
                                           out, nullptr);
}